// Round 7
// baseline (1568.624 us; speedup 1.0000x reference)
//
#include <hip/hip_runtime.h>
#include <cstdint>
#include <cstddef>

// BooleanReservoir — persistent cooperative kernel, v6 (data-flow tag sync).
// lane = batch; states[node] = u64 (bit b = batch b). Packed LUT + adjacency in
// LDS. No per-step barrier: each state half-word is {state32, tag32} stored as a
// relaxed agent-scope u64 atomic; consumers poll tags (exact match s). Ring of 8
// buffers + global barrier every 6 steps bounds skew to 6 < 7 => ring reuse safe.
// Producer->consumer latency = 2 IF hops (store visible + poll observe), vs ~4.5
// hops for the per-step barrier designs (R4/R5, both ~4.5us/step).

#define N_NODES   20000
#define N_INPUT   64
#define K_MAX     12
#define T_STEPS   128
#define N_BATCH   64
#define N_OUT     10
#define N_FEAT    (N_NODES - N_INPUT)   // 19936
#define DUMMY_NODE 20000                // always-zero state word
#define ST_WORDS  20004

#define NBLK 256
#define NTHR 1024                       // 16 waves/block, 1 block/CU
#define NPB  78                         // nodes/block: 256*78 = 19968 >= 19936
#define NPB_PAD 80
#define R_BUF 8                         // ring depth (power of 2)
#define M_BAR 6                         // barrier every 6 steps; 6 % 8 != 0 => safe
#define GO_CNT 8
#define AS     32                       // barrier slot stride: 32 u32 = 128 B

typedef unsigned long long u64;

#define A_LOAD(p)    __hip_atomic_load((p), __ATOMIC_RELAXED, __HIP_MEMORY_SCOPE_AGENT)
#define A_STORE(p,v) __hip_atomic_store((p), (v), __ATOMIC_RELAXED, __HIP_MEMORY_SCOPE_AGENT)

// ---------------- pack x: xp[t][b] = bits j of x[b][t][j] ----------------
__global__ __launch_bounds__(256) void pack_x_kernel(const int* __restrict__ x,
                                                     u64* __restrict__ xp) {
  const int t = blockIdx.x;
  const int wave = threadIdx.x >> 6, lane = threadIdx.x & 63;
  for (int b = wave; b < N_BATCH; b += 4) {
    int v = x[((size_t)b * T_STEPS + t) * 64 + lane];
    u64 bal = __ballot(v != 0);
    if (lane == 0) xp[(size_t)t * N_BATCH + b] = bal;
  }
}

// -------- init ring[0] (tag 0), wcol, u(0), barrier slots --------
__global__ __launch_bounds__(256) void init_kernel(const int* __restrict__ inis,
                                                   const int* __restrict__ w_in,
                                                   const u64* __restrict__ xp,
                                                   u64* __restrict__ Ar,
                                                   u64* __restrict__ Br,
                                                   u64* __restrict__ wcol,
                                                   unsigned* __restrict__ arr,
                                                   unsigned* __restrict__ go) {
  if (blockIdx.x < 79) {
    int n = blockIdx.x * 256 + threadIdx.x;
    if (n >= N_INPUT && n < ST_WORDS) {
      u64 w = (n < N_NODES && inis[n] != 0) ? ~0ull : 0ull;   // dummy/pad -> 0
      Ar[n] = (w & 0xFFFFFFFFull) << 32;     // {state_lo, tag=0}
      Br[n] = (w >> 32) << 32;               // {state_hi, tag=0}
    }
  } else {
    const int wave = threadIdx.x >> 6, lane = threadIdx.x & 63;
    u64 xw = xp[lane];                       // xp[t=0][b=lane]
    for (int i = wave; i < 64; i += 4) {
      int wv = w_in[(size_t)lane * 64 + i];  // lane = j
      u64 wc = __ballot(wv != 0);
      if (lane == 0) wcol[i] = wc;
      u64 ub = __ballot((xw & wc) != 0);     // u(0)[b][i], lane = b
      if (lane == 0) {
        Ar[i] = (ub & 0xFFFFFFFFull) << 32;
        Br[i] = (ub >> 32) << 32;
      }
    }
    arr[threadIdx.x * AS] = 0u;              // 256 arrival slots (ws re-poisoned)
    if (threadIdx.x < GO_CNT) go[threadIdx.x * AS] = 0u;
  }
}

// -------- precompute u(t): u_all[t*64+i] bit b = (xp[t][b] & wcol[i]) != 0 --------
__global__ __launch_bounds__(64) void u_pre_kernel(const u64* __restrict__ xp,
                                                   const u64* __restrict__ wcol,
                                                   u64* __restrict__ u_all) {
  const int t = blockIdx.x, lane = threadIdx.x;
  u64 xw = xp[(size_t)t * N_BATCH + lane];   // lane = batch
  for (int i = 0; i < 64; i++) {
    u64 ub = __ballot((xw & wcol[i]) != 0);
    if (lane == 0) u_all[(size_t)t * 64 + i] = ub;
  }
}

// ---- 64x64 bit transpose: lane l holds row l; returns lane b holding column b ----
__device__ __forceinline__ u64 bit_transpose64(u64 w, int lane) {
  const u64 LO0 = 0x00000000FFFFFFFFull, LO1 = 0x0000FFFF0000FFFFull,
            LO2 = 0x00FF00FF00FF00FFull, LO3 = 0x0F0F0F0F0F0F0F0Full,
            LO4 = 0x3333333333333333ull, LO5 = 0x5555555555555555ull;
#define XP_STAGE(d, LO)                                                  \
  {                                                                      \
    u64 p = (u64)__shfl_xor((long long)w, (d), 64);                      \
    if (lane & (d)) w = ((p >> (d)) & (LO)) | (w & ~(LO));               \
    else            w = (w & (LO)) | ((p << (d)) & ~(LO));               \
  }
  XP_STAGE(32, LO0) XP_STAGE(16, LO1) XP_STAGE(8, LO2)
  XP_STAGE(4,  LO3) XP_STAGE(2,  LO4) XP_STAGE(1, LO5)
#undef XP_STAGE
  return w;
}

// ---------------- persistent reservoir: all 128 steps ----------------
__global__ __launch_bounds__(NTHR) void reservoir_kernel(
    const int* __restrict__ lut, const int* __restrict__ adj,
    const int* __restrict__ mask, const int* __restrict__ inis,
    const u64* __restrict__ u_all, u64* __restrict__ Aring,
    u64* __restrict__ Bring, unsigned* __restrict__ arr,
    unsigned* __restrict__ go) {
  __shared__ u64 lut_lds[NPB_PAD * 64];        // 40960 B
  __shared__ int adj_lds[NPB_PAD * K_MAX];     //  3840 B
  __shared__ unsigned char hn_lds[NPB_PAD];
  __shared__ volatile unsigned lds_scan[4];

  const int bi = blockIdx.x;
  const int tid = threadIdx.x;
  const int wave = tid >> 6, lane = tid & 63;
  const int base = N_INPUT + bi * NPB;
  const int nloc = min(NPB, N_NODES - base);   // last block: 46

  // ---- prologue: adjacency (slot-REVERSED: slot j at offset 11-j) + hn ----
  if (tid < NPB_PAD) {
    int i = tid, h = 0;
    if (i < nloc) {
      for (int j = 0; j < K_MAX; j++) {
        int m = mask[(size_t)(base + i) * K_MAX + j];
        int a = adj[(size_t)(base + i) * K_MAX + j];
        adj_lds[i * K_MAX + (K_MAX - 1 - j)] = m ? a : DUMMY_NODE;
        h |= m;
      }
    } else {
      for (int j = 0; j < K_MAX; j++) adj_lds[i * K_MAX + j] = DUMMY_NODE;
    }
    hn_lds[i] = (unsigned char)(h ? 1 : 0);
  }
  if (tid < 4) lds_scan[tid] = 0u;

  // ---- prologue: pack this block's LUT slice into LDS ----
  const int nwords = nloc * 64;
  const int* lp = lut + (size_t)base * 4096;
  for (int w0 = wave * 8; w0 < nwords; w0 += 128) {   // 16 waves x 8 words
    int v[8];
#pragma unroll
    for (int q = 0; q < 8; q++) {
      int widx = w0 + q;
      v[q] = (widx < nwords) ? lp[(size_t)widx * 64 + lane] : 0;   // coalesced 256B
    }
#pragma unroll
    for (int q = 0; q < 8; q++) {
      int widx = w0 + q;
      u64 bal = __ballot(v[q] != 0);
      if (lane == 0 && widx < nwords) lut_lds[widx] = bal;
    }
  }
  __syncthreads();   // block-local; ring[0] from init_kernel (launch-ordered)

  const int l0 = wave * 5;
  const int cnt5 = min(5, nloc - l0);          // <=0 for idle waves (block 255 w10+)
  const int a_reg = (lane < 60) ? adj_lds[l0 * K_MAX + lane] : DUMMY_NODE;
  // my node's current state (for hn==0 keep-and-republish); nodes here are >= 64
  u64 mystate = 0;
  if (cnt5 > 0 && lane < cnt5)
    mystate = (inis[base + l0 + lane] != 0) ? ~0ull : 0ull;

  // ---- 128 steps, tag-synced ----
  for (int s = 0; s < T_STEPS; s++) {
    const unsigned tg = (unsigned)s;
    const u64* Ac = Aring + (size_t)(s & 7) * ST_WORDS;
    const u64* Bc = Bring + (size_t)(s & 7) * ST_WORDS;
    u64 newS = 0;

    if (cnt5 > 0) {                            // node wave (wave-uniform)
      u64 va = 0, vb = 0;
      if (lane < 60) {
        va = A_LOAD(Ac + a_reg);
        vb = A_LOAD(Bc + a_reg);
      }
      int guard = 0;
      for (;;) {                               // poll: both halves' tags == s
        bool stale = (lane < 60) &&
                     (((unsigned)va != tg) || ((unsigned)vb != tg));
        if (!__any(stale)) break;
        if (++guard > (1 << 17)) break;        // defensive: fail, don't hang
        if (stale) {
          va = A_LOAD(Ac + a_reg);
          vb = A_LOAD(Bc + a_reg);
        }
      }
      u64 w64 = (va >> 32) | (vb & 0xFFFFFFFF00000000ull);
      w64 = bit_transpose64(w64, lane);        // lane b: 60 index bits for batch b

      u64 keep = 0;
#pragma unroll
      for (int i = 0; i < 5; i++) {
        if (i < cnt5) {
          unsigned idx = (unsigned)(w64 >> (12 * i)) & 0xFFFu;   // MSB-first
          u64 g = lut_lds[(l0 + i) * 64 + (idx >> 6)];
          u64 res = __ballot((g >> (idx & 63)) & 1ull);
          if (lane == i) keep = res;
        }
      }
      if (lane < cnt5) {
        newS = hn_lds[l0 + lane] ? keep : mystate;   // no-neigh: keep, republish
        mystate = newS;
      }
    }

    // ---- publish step s+1 into ring[(s+1)&7] ----
    const unsigned tg1 = (unsigned)(s + 1);
    u64* An = Aring + (size_t)((s + 1) & 7) * ST_WORDS;
    u64* Bn = Bring + (size_t)((s + 1) & 7) * ST_WORDS;
    if (cnt5 > 0) {
      // one 10-lane store: lanes 0..4 A-halves, lanes 8..12 B-halves
      u64 Sv = (u64)__shfl((long long)newS, lane & 7);
      bool stl = ((lane & 7) < cnt5) && (lane < 16) && ((lane & 7) == lane || lane >= 8);
      u64 word = (lane < 8) ? (((Sv & 0xFFFFFFFFull) << 32) | tg1)
                            : (((Sv >> 32) << 32) | tg1);
      u64* p = ((lane < 8) ? An : Bn) + (base + l0 + (lane & 7));
      if (stl) A_STORE(p, word);
    } else if (bi == NBLK - 1 && wave == 10) {
      if (s + 1 < T_STEPS) {                   // publish u(s+1) words 0..63
        u64 S = u_all[(size_t)(s + 1) * 64 + lane];
        A_STORE(&An[lane], ((S & 0xFFFFFFFFull) << 32) | tg1);
        A_STORE(&Bn[lane], ((S >> 32) << 32) | tg1);
      }
    } else if (bi == NBLK - 1 && wave == 11) {
      if (lane == 0 && s + 1 < T_STEPS) {      // publish dummy (state 0)
        A_STORE(&An[DUMMY_NODE], (u64)tg1);
        A_STORE(&Bn[DUMMY_NODE], (u64)tg1);
      }
    }

    // ---- global barrier every M_BAR steps: bounds skew for ring reuse ----
    if (s != T_STEPS - 1 && (s % M_BAR) == (M_BAR - 1)) {
      const unsigned e = (unsigned)(s / M_BAR) + 1;
      __syncthreads();                         // drain all waves' stores to IF
      if (wave == 0 && lane == 0) A_STORE(&arr[bi * AS], e);
      if (bi == 0 && wave < 4) {               // scan 256 arrival slots
        const int idx = (wave * 64 + lane) * AS;
        for (;;) {
          unsigned v = A_LOAD(&arr[idx]);
          if (__all(v >= e)) break;
        }
        if (lane == 0) lds_scan[wave] = e;
      }
      if (bi == 0 && wave == 0) {
        while (lds_scan[0] < e || lds_scan[1] < e ||
               lds_scan[2] < e || lds_scan[3] < e) {}
        if (lane < GO_CNT) A_STORE(&go[lane * AS], e);
      }
      if (wave == 0) {
        while (A_LOAD(&go[(bi & (GO_CNT - 1)) * AS]) < e) {}   // same-addr poll
      }
      __syncthreads();
    }
  }
}

// ------- readout: sigmoid(feats @ W_out^T + b_out); final states = ring[0] -------
__global__ __launch_bounds__(256) void readout_kernel(const u64* __restrict__ Ar,
                                                      const u64* __restrict__ Br,
                                                      const float* __restrict__ Wout,
                                                      const float* __restrict__ bout,
                                                      float* __restrict__ out) {
  const int b = blockIdx.x / N_OUT;
  const int o = blockIdx.x % N_OUT;
  float acc = 0.f;
  for (int n = threadIdx.x; n < N_FEAT; n += 256) {
    u64 s = (Ar[N_INPUT + n] >> 32) | ((Br[N_INPUT + n] >> 32) << 32);
    float w = Wout[(size_t)o * N_FEAT + n];
    acc += ((s >> b) & 1ull) ? w : 0.f;
  }
  for (int off = 32; off > 0; off >>= 1) acc += __shfl_down(acc, off);
  __shared__ float red[4];
  const int wave = threadIdx.x >> 6, lane = threadIdx.x & 63;
  if (lane == 0) red[wave] = acc;
  __syncthreads();
  if (threadIdx.x == 0) {
    float tot = red[0] + red[1] + red[2] + red[3] + bout[o];
    out[(size_t)b * N_OUT + o] = 1.f / (1.f + __expf(-tot));
  }
}

extern "C" void kernel_launch(void* const* d_in, const int* in_sizes, int n_in,
                              void* d_out, int out_size, void* d_ws, size_t ws_size,
                              hipStream_t stream) {
  const int* x    = (const int*)d_in[0];
  const int* w_in = (const int*)d_in[1];
  const int* adj  = (const int*)d_in[2];
  const int* mask = (const int*)d_in[3];
  const int* lut  = (const int*)d_in[4];
  const int* inis = (const int*)d_in[5];
  const float* Wout = (const float*)d_in[6];
  const float* bout = (const float*)d_in[7];
  float* out = (float*)d_out;

  char* ws = (char*)d_ws;
  size_t off = 0;
  auto alloc = [&](size_t bytes) -> void* {
    void* p = ws + off;
    off += (bytes + 255) & ~(size_t)255;
    return p;
  };
  u64* Aring = (u64*)alloc((size_t)R_BUF * ST_WORDS * 8);     // 1.28 MB
  u64* Bring = (u64*)alloc((size_t)R_BUF * ST_WORDS * 8);     // 1.28 MB
  u64* xp    = (u64*)alloc((size_t)T_STEPS * N_BATCH * 8);
  u64* wcol  = (u64*)alloc(64 * 8);
  u64* u_all = (u64*)alloc((size_t)T_STEPS * 64 * 8);         // 64 KB
  unsigned* arr = (unsigned*)alloc((size_t)NBLK * AS * 4);    // 32 KB
  unsigned* go  = (unsigned*)alloc((size_t)GO_CNT * AS * 4);
  (void)ws_size; (void)in_sizes; (void)n_in; (void)out_size;

  hipLaunchKernelGGL(pack_x_kernel, dim3(T_STEPS), dim3(256), 0, stream, x, xp);
  hipLaunchKernelGGL(init_kernel, dim3(80), dim3(256), 0, stream,
                     inis, w_in, xp, Aring, Bring, wcol, arr, go);
  hipLaunchKernelGGL(u_pre_kernel, dim3(T_STEPS), dim3(64), 0, stream,
                     xp, wcol, u_all);

  void* args[] = {(void*)&lut, (void*)&adj, (void*)&mask, (void*)&inis,
                  (void*)&u_all, (void*)&Aring, (void*)&Bring,
                  (void*)&arr, (void*)&go};
  hipLaunchCooperativeKernel((const void*)reservoir_kernel,
                             dim3(NBLK), dim3(NTHR), args, 0, stream);

  // final states carry tag 128, live in ring[128 & 7] = ring[0]
  hipLaunchKernelGGL(readout_kernel, dim3(N_BATCH * N_OUT), dim3(256), 0, stream,
                     Aring, Bring, Wout, bout, out);
}

// Round 8
// 1052.441 us; speedup vs baseline: 1.4905x; 1.4905x over previous
//
#include <hip/hip_runtime.h>
#include <cstdint>
#include <cstddef>

// BooleanReservoir — persistent cooperative kernel, v7 (never-reused ring).
// lane = batch; states[node] = u64 (bit b = batch b). Packed LUT + adjacency in
// LDS. Each step s publishes into ring slot s+1 (agent-scope stores, visible at
// IF). Slots are NEVER reused => post-barrier gathers are PLAIN CACHED loads:
// per-XCD L2 dedupes 245K scattered sc1 requests/step (R4..R7's bottleneck,
// ~20-25 req/cyc IF service) into ~2.5K line fetches/XCD/step. One-time
// agent-acquire fence per block clears poison/stale lines; no per-step cache ops.

#define N_NODES   20000
#define N_INPUT   64
#define K_MAX     12
#define T_STEPS   128
#define N_BATCH   64
#define N_OUT     10
#define N_FEAT    (N_NODES - N_INPUT)   // 19936
#define DUMMY_NODE 20000                // always-zero state word
#define ST_STRIDE 20008                 // words/slot, 64B-aligned (20008*8 % 64 == 0)
#define R_DEPTH   (T_STEPS + 1)         // 129 slots, write-once

#define NBLK 256
#define NTHR 1024                       // 16 waves/block, 1 block/CU
#define NPB  78                         // nodes/block: 256*78 = 19968 >= 19936
#define NPB_PAD 80
#define GO_CNT 8
#define AS     32                       // barrier slot stride: 32 u32 = 128 B

typedef unsigned long long u64;

#define A_LOAD(p)    __hip_atomic_load((p), __ATOMIC_RELAXED, __HIP_MEMORY_SCOPE_AGENT)
#define A_STORE(p,v) __hip_atomic_store((p), (v), __ATOMIC_RELAXED, __HIP_MEMORY_SCOPE_AGENT)

// ---------------- pack x: xp[t][b] = bits j of x[b][t][j] ----------------
__global__ __launch_bounds__(256) void pack_x_kernel(const int* __restrict__ x,
                                                     u64* __restrict__ xp) {
  const int t = blockIdx.x;
  const int wave = threadIdx.x >> 6, lane = threadIdx.x & 63;
  for (int b = wave; b < N_BATCH; b += 4) {
    int v = x[((size_t)b * T_STEPS + t) * 64 + lane];
    u64 bal = __ballot(v != 0);
    if (lane == 0) xp[(size_t)t * N_BATCH + b] = bal;
  }
}

// -------- init ring slot 0, per-slot dummy words, wcol, barrier slots --------
// Plain stores: kernel-end release flushes to memory; reservoir re-reads after
// its dispatch acquire + explicit per-block agent-acquire fence.
__global__ __launch_bounds__(256) void init_kernel(const int* __restrict__ inis,
                                                   const int* __restrict__ w_in,
                                                   u64* __restrict__ ring,
                                                   u64* __restrict__ wcol,
                                                   unsigned* __restrict__ arr,
                                                   unsigned* __restrict__ go) {
  if (blockIdx.x < 79) {
    int n = blockIdx.x * 256 + threadIdx.x;
    if (n >= N_INPUT && n < N_NODES)
      ring[n] = (inis[n] != 0) ? ~0ull : 0ull;         // slot 0 state
  } else {
    const int wave = threadIdx.x >> 6, lane = threadIdx.x & 63;
    for (int i = wave; i < 64; i += 4) {
      int wv = w_in[(size_t)lane * 64 + i];            // lane = j
      u64 wc = __ballot(wv != 0);
      if (lane == 0) wcol[i] = wc;
    }
    // dummy word (always 0) in every slot; pads never read
    if (threadIdx.x < R_DEPTH)
      ring[(size_t)threadIdx.x * ST_STRIDE + DUMMY_NODE] = 0ull;
    arr[threadIdx.x * AS] = 0u;                        // 256 arrival slots
    if (threadIdx.x < GO_CNT) go[threadIdx.x * AS] = 0u;
  }
}

// -------- precompute u(t): u_all[t*64+i] bit b = (xp[t][b] & wcol[i]) != 0 --------
__global__ __launch_bounds__(64) void u_pre_kernel(const u64* __restrict__ xp,
                                                   const u64* __restrict__ wcol,
                                                   u64* __restrict__ u_all) {
  const int t = blockIdx.x, lane = threadIdx.x;
  u64 xw = xp[(size_t)t * N_BATCH + lane];             // lane = batch
  for (int i = 0; i < 64; i++) {
    u64 ub = __ballot((xw & wcol[i]) != 0);
    if (lane == 0) u_all[(size_t)t * 64 + i] = ub;
  }
}

// ---- 64x64 bit transpose: lane l holds row l; returns lane b holding column b ----
__device__ __forceinline__ u64 bit_transpose64(u64 w, int lane) {
  const u64 LO0 = 0x00000000FFFFFFFFull, LO1 = 0x0000FFFF0000FFFFull,
            LO2 = 0x00FF00FF00FF00FFull, LO3 = 0x0F0F0F0F0F0F0F0Full,
            LO4 = 0x3333333333333333ull, LO5 = 0x5555555555555555ull;
#define XP_STAGE(d, LO)                                                  \
  {                                                                      \
    u64 p = (u64)__shfl_xor((long long)w, (d), 64);                      \
    if (lane & (d)) w = ((p >> (d)) & (LO)) | (w & ~(LO));               \
    else            w = (w & (LO)) | ((p << (d)) & ~(LO));               \
  }
  XP_STAGE(32, LO0) XP_STAGE(16, LO1) XP_STAGE(8, LO2)
  XP_STAGE(4,  LO3) XP_STAGE(2,  LO4) XP_STAGE(1, LO5)
#undef XP_STAGE
  return w;
}

// ---------------- persistent reservoir: all 128 steps ----------------
__global__ __launch_bounds__(NTHR) void reservoir_kernel(
    const int* __restrict__ lut, const int* __restrict__ adj,
    const int* __restrict__ mask, const int* __restrict__ inis,
    const u64* __restrict__ u_all, u64* __restrict__ ring,
    unsigned* __restrict__ arr, unsigned* __restrict__ go) {
  __shared__ u64 lut_lds[NPB_PAD * 64];        // 40960 B
  __shared__ int adj_lds[NPB_PAD * K_MAX];     //  3840 B
  __shared__ unsigned char hn_lds[NPB_PAD];
  __shared__ volatile unsigned lds_scan[4];

  const int bi = blockIdx.x;
  const int tid = threadIdx.x;
  const int wave = tid >> 6, lane = tid & 63;
  const int base = N_INPUT + bi * NPB;
  const int nloc = min(NPB, N_NODES - base);   // last block: 46

  // one-time cache scrub: drop poison/prior-iteration lines from L1/L2 so all
  // later PLAIN ring/u_all loads fetch fresh, post-publish data. One inv/block
  // (R2 lesson: per-step/per-wave cache ops serialize catastrophically).
  if (wave == 0) __builtin_amdgcn_fence(__ATOMIC_ACQUIRE, "agent");

  // ---- prologue: adjacency (slot-REVERSED: slot j at offset 11-j) + hn ----
  if (tid < NPB_PAD) {
    int i = tid, h = 0;
    if (i < nloc) {
      for (int j = 0; j < K_MAX; j++) {
        int m = mask[(size_t)(base + i) * K_MAX + j];
        int a = adj[(size_t)(base + i) * K_MAX + j];
        adj_lds[i * K_MAX + (K_MAX - 1 - j)] = m ? a : DUMMY_NODE;
        h |= m;
      }
    } else {
      for (int j = 0; j < K_MAX; j++) adj_lds[i * K_MAX + j] = DUMMY_NODE;
    }
    hn_lds[i] = (unsigned char)(h ? 1 : 0);
  }
  if (tid < 4) lds_scan[tid] = 0u;

  // ---- prologue: pack this block's LUT slice into LDS ----
  const int nwords = nloc * 64;
  const int* lp = lut + (size_t)base * 4096;
  for (int w0 = wave * 8; w0 < nwords; w0 += 128) {   // 16 waves x 8 words
    int v[8];
#pragma unroll
    for (int q = 0; q < 8; q++) {
      int widx = w0 + q;
      v[q] = (widx < nwords) ? lp[(size_t)widx * 64 + lane] : 0;   // coalesced 256B
    }
#pragma unroll
    for (int q = 0; q < 8; q++) {
      int widx = w0 + q;
      u64 bal = __ballot(v[q] != 0);
      if (lane == 0 && widx < nwords) lut_lds[widx] = bal;
    }
  }
  __syncthreads();   // fence + LDS ready; slot 0 from init (launch-ordered)

  const int l0 = wave * 5;
  const int cnt5 = min(5, nloc - l0);          // <=0 for idle waves
  const int a_reg = (lane < 60) ? adj_lds[l0 * K_MAX + lane] : DUMMY_NODE;
  const bool store_ln = (lane < cnt5);
  const bool myhn = store_ln && hn_lds[l0 + lane];
  u64 mystate = 0;                             // for hn==0 keep-and-republish
  if (store_ln) mystate = (inis[base + l0 + lane] != 0) ? ~0ull : 0ull;

  // ---- 128 steps ----
  for (int s = 0; s < T_STEPS; s++) {
    const u64* slot_cur = ring + (size_t)s * ST_STRIDE;
    u64* slot_nxt      = ring + (size_t)(s + 1) * ST_STRIDE;

    if (cnt5 > 0) {                            // node wave (wave-uniform)
      // gather: PLAIN cached load (write-once addresses; L2 dedupes per XCD)
      u64 w = 0;
      if (lane < 60) {
        const u64* p = (a_reg < N_INPUT) ? (u_all + (size_t)s * 64 + a_reg)
                                         : (slot_cur + a_reg);
        w = *p;
      }
      w = bit_transpose64(w, lane);            // lane b: 60 index bits for batch b

      u64 keep = 0;
#pragma unroll
      for (int i = 0; i < 5; i++) {
        if (i < cnt5) {
          unsigned idx = (unsigned)(w >> (12 * i)) & 0xFFFu;   // MSB-first
          u64 g = lut_lds[(l0 + i) * 64 + (idx >> 6)];
          u64 res = __ballot((g >> (idx & 63)) & 1ull);
          if (lane == i) keep = res;
        }
      }
      if (store_ln) {
        u64 newS = myhn ? keep : mystate;      // no-neigh: keep, republish
        mystate = newS;
        // publish: agent store -> coherence point (consumers plain-load later)
        A_STORE(&slot_nxt[base + l0 + lane], newS);
      }
    }

    // ---- per-step grid barrier (R5-proven gbar; no cache ops) ----
    if (s != T_STEPS - 1) {
      const unsigned e = (unsigned)(s + 1);
      __syncthreads();                         // all waves drain stores to IF
      if (wave == 0 && lane == 0) A_STORE(&arr[bi * AS], e);
      if (bi == 0 && wave < 4) {               // scan 256 arrival slots
        const int idx = (wave * 64 + lane) * AS;
        for (;;) {
          unsigned v = A_LOAD(&arr[idx]);
          if (__all(v >= e)) break;
        }
        if (lane == 0) lds_scan[wave] = e;
      }
      if (bi == 0 && wave == 0) {
        while (lds_scan[0] < e || lds_scan[1] < e ||
               lds_scan[2] < e || lds_scan[3] < e) {}
        if (lane < GO_CNT) A_STORE(&go[lane * AS], e);
      }
      if (wave == 0) {
        while (A_LOAD(&go[(bi & (GO_CNT - 1)) * AS]) < e) {}   // same-addr poll
      }
      __syncthreads();
    }
  }
}

// ------- readout: sigmoid(feats @ W_out^T + b_out) from ring slot 128 -------
__global__ __launch_bounds__(256) void readout_kernel(const u64* __restrict__ st,
                                                      const float* __restrict__ Wout,
                                                      const float* __restrict__ bout,
                                                      float* __restrict__ out) {
  const int b = blockIdx.x / N_OUT;
  const int o = blockIdx.x % N_OUT;
  float acc = 0.f;
  for (int n = threadIdx.x; n < N_FEAT; n += 256) {
    u64 s = st[N_INPUT + n];
    float w = Wout[(size_t)o * N_FEAT + n];
    acc += ((s >> b) & 1ull) ? w : 0.f;
  }
  for (int off = 32; off > 0; off >>= 1) acc += __shfl_down(acc, off);
  __shared__ float red[4];
  const int wave = threadIdx.x >> 6, lane = threadIdx.x & 63;
  if (lane == 0) red[wave] = acc;
  __syncthreads();
  if (threadIdx.x == 0) {
    float tot = red[0] + red[1] + red[2] + red[3] + bout[o];
    out[(size_t)b * N_OUT + o] = 1.f / (1.f + __expf(-tot));
  }
}

extern "C" void kernel_launch(void* const* d_in, const int* in_sizes, int n_in,
                              void* d_out, int out_size, void* d_ws, size_t ws_size,
                              hipStream_t stream) {
  const int* x    = (const int*)d_in[0];
  const int* w_in = (const int*)d_in[1];
  const int* adj  = (const int*)d_in[2];
  const int* mask = (const int*)d_in[3];
  const int* lut  = (const int*)d_in[4];
  const int* inis = (const int*)d_in[5];
  const float* Wout = (const float*)d_in[6];
  const float* bout = (const float*)d_in[7];
  float* out = (float*)d_out;

  char* ws = (char*)d_ws;
  size_t off = 0;
  auto alloc = [&](size_t bytes) -> void* {
    void* p = ws + off;
    off += (bytes + 255) & ~(size_t)255;
    return p;
  };
  u64* ring  = (u64*)alloc((size_t)R_DEPTH * ST_STRIDE * 8);  // 20.65 MB (ws ~1.3 GB)
  u64* xp    = (u64*)alloc((size_t)T_STEPS * N_BATCH * 8);
  u64* wcol  = (u64*)alloc(64 * 8);
  u64* u_all = (u64*)alloc((size_t)T_STEPS * 64 * 8);         // 64 KB
  unsigned* arr = (unsigned*)alloc((size_t)NBLK * AS * 4);    // 32 KB
  unsigned* go  = (unsigned*)alloc((size_t)GO_CNT * AS * 4);
  (void)ws_size; (void)in_sizes; (void)n_in; (void)out_size;

  hipLaunchKernelGGL(pack_x_kernel, dim3(T_STEPS), dim3(256), 0, stream, x, xp);
  hipLaunchKernelGGL(init_kernel, dim3(80), dim3(256), 0, stream,
                     inis, w_in, ring, wcol, arr, go);
  hipLaunchKernelGGL(u_pre_kernel, dim3(T_STEPS), dim3(64), 0, stream,
                     xp, wcol, u_all);

  void* args[] = {(void*)&lut, (void*)&adj, (void*)&mask, (void*)&inis,
                  (void*)&u_all, (void*)&ring, (void*)&arr, (void*)&go};
  hipLaunchCooperativeKernel((const void*)reservoir_kernel,
                             dim3(NBLK), dim3(NTHR), args, 0, stream);

  // final states live in ring slot 128
  hipLaunchKernelGGL(readout_kernel, dim3(N_BATCH * N_OUT), dim3(256), 0, stream,
                     ring + (size_t)T_STEPS * ST_STRIDE, Wout, bout, out);
}